// Round 7
// baseline (519.232 us; speedup 1.0000x reference)
//
#include <hip/hip_runtime.h>
#include <hip/hip_bf16.h>

// GGCN: g1=relu(A@(x@W1)+b1); g2=relu(A@(g1@W2)+b2); out=relu(g2@Wd1+bd1)@Wd2+bd2
// N=16384, F=32, H=64, A dense f32 (1.07 GB, read 2x -> HBM floor ~341us).
// R7: BM=128. grid 256 = 128 rowblks x 2 K-halves; 512-thr blocks, 8 waves =
// 2 row-halves x 4 K-quarters; each wave 64 rows x 2048k, K-step 32, wave-private
// dbuf LDS, barrier-free (R6 structure). Unique Ht per dispatch 512->256 MB.
// 2 waves/SIMD (vs R6's 1). Cross-block K-half partials in ws + reduce kernel.

typedef __bf16 bf16x8 __attribute__((ext_vector_type(8)));
typedef float  f32x16 __attribute__((ext_vector_type(16)));
typedef float  f32x4v __attribute__((ext_vector_type(4)));
typedef int    i32x4  __attribute__((ext_vector_type(4)));

#define NNODE 16384
#define KDIM  16384
#define HCOL  64

__device__ inline i32x4 pack8(f32x4v a, f32x4v b){
  bf16x8 t;
  t[0]=(__bf16)a[0]; t[1]=(__bf16)a[1]; t[2]=(__bf16)a[2]; t[3]=(__bf16)a[3];
  t[4]=(__bf16)b[0]; t[5]=(__bf16)b[1]; t[6]=(__bf16)b[2]; t[7]=(__bf16)b[3];
  return __builtin_bit_cast(i32x4, t);
}
#define BC(x) __builtin_bit_cast(bf16x8, x)

// ---------------- big kernel: gP[kh] = A[:, kh-half] @ Ht^T ----------------
__global__ __launch_bounds__(512, 2) void gcn_layer_kernel(
    const float* __restrict__ A,      // [16384][16384] f32
    const __bf16* __restrict__ Ht,    // [64][16384] bf16 (transposed H)
    float* __restrict__ gP)           // [2][16384][64] f32 partials
{
  __shared__ i32x4 smem[8192];        // 128 KB. [0..4095]=sA, [4096..8191]=sH
                                      // per (wave,buf): 256 i32x4 = 4 KB tile

  const int tid  = threadIdx.x;
  const int lane = tid & 63;
  const int wid  = tid >> 6;          // 0..7
  const int kw   = wid & 3;           // K-quarter within this block's K-half
  const int rh   = wid >> 2;          // row-half 0/1
  const int bid  = blockIdx.x;
  const int kh   = bid & 1;           // K-half (low bit -> same-XCD blocks share Ht half)
  const int rowblk = bid >> 1;
  const int rowbase = rowblk*128 + rh*64;

  const int srow = lane >> 2;         // 0..15 staging row-in-group
  const int cc   = lane & 3;          // logical 16B-chunk (4 per 32k row)
  const int swz  = cc ^ (srow & 3);   // XOR swizzle (row&3 == srow&3)
  const int r    = lane & 31;
  const int hsub = lane >> 5;         // 8-k half of the 16-k MFMA window
  const int x3   = r & 3;

  const size_t k0 = (size_t)kh*8192 + (size_t)kw*2048;

  i32x4* sAw = smem + wid*512;        // this wave's A region (2 bufs x 256)
  i32x4* sHw = smem + 4096 + wid*512;

  f32x4v ra[8]; i32x4 rhh[4];

  const float*  pA0 = A  + (size_t)(rowbase + srow)*KDIM + k0 + (size_t)cc*8;
  const __bf16* pH0 = Ht + (size_t)srow*KDIM           + k0 + (size_t)cc*8;

  auto stage_load = [&](int t){
    const float* pA = pA0 + (size_t)t*32;
    #pragma unroll
    for (int pi=0; pi<4; ++pi){                     // rows pi*16+srow (64 rows)
      const float* p = pA + (size_t)pi*16*KDIM;
      ra[2*pi]   = __builtin_nontemporal_load((const f32x4v*)p);   // A: stream
      ra[2*pi+1] = __builtin_nontemporal_load((const f32x4v*)(p+4));
    }
    const __bf16* pH = pH0 + (size_t)t*32;
    #pragma unroll
    for (int pi=0; pi<4; ++pi)
      rhh[pi] = *(const i32x4*)(pH + (size_t)pi*16*KDIM);          // Ht: L2
  };

  auto stage_write = [&](int buf){
    i32x4* dA = sAw + buf*256;
    #pragma unroll
    for (int pi=0; pi<4; ++pi)
      dA[(pi*16 + srow)*4 + swz] = pack8(ra[2*pi], ra[2*pi+1]);
    i32x4* dH = sHw + buf*256;
    #pragma unroll
    for (int pi=0; pi<4; ++pi)
      dH[(pi*16 + srow)*4 + swz] = rhh[pi];
  };

  f32x16 acc00 = {}, acc01 = {}, acc10 = {}, acc11 = {};

  auto compute = [&](int buf){
    const i32x4* bA = sAw + buf*256;
    const i32x4* bH = sHw + buf*256;
    #pragma unroll
    for (int kk=0; kk<2; ++kk){
      int c = (kk*2 + hsub) ^ x3;
      bf16x8 a0 = BC(bA[r*4 + c]);
      bf16x8 a1 = BC(bA[(r+32)*4 + c]);
      bf16x8 b0 = BC(bH[r*4 + c]);
      bf16x8 b1 = BC(bH[(r+32)*4 + c]);
      acc00 = __builtin_amdgcn_mfma_f32_32x32x16_bf16(a0, b0, acc00, 0,0,0);
      acc01 = __builtin_amdgcn_mfma_f32_32x32x16_bf16(a0, b1, acc01, 0,0,0);
      acc10 = __builtin_amdgcn_mfma_f32_32x32x16_bf16(a1, b0, acc10, 0,0,0);
      acc11 = __builtin_amdgcn_mfma_f32_32x32x16_bf16(a1, b1, acc11, 0,0,0);
    }
  };

  // barrier-free per-wave dbuf pipeline over 64 tiles (2048 k, 32 k each)
  stage_load(0);
  stage_write(0);
  stage_load(1);
  #pragma unroll 1
  for (int t=0; t<63; ++t){
    compute(t&1);
    stage_write((t+1)&1);
    if (t < 62) stage_load(t+2);
  }
  compute(1);                   // tile 63

  __syncthreads();              // red aliases all waves' tile regions

  // split-K=4 reduce within each row-half group; kw=0 stores partial for kh
  float* red = (float*)smem;    // per rh: 3 x 64x64 f32 = 48 KB
  if (kw > 0){
    float* rd = red + rh*12288 + (size_t)(kw-1)*4096;
    #pragma unroll
    for (int j=0; j<16; ++j){
      int rr = (j&3) + 8*(j>>2) + 4*hsub;          // C/D layout [verified R1..R6]
      rd[(rr   )*64 + r]      = acc00[j];
      rd[(rr   )*64 + 32 + r] = acc01[j];
      rd[(rr+32)*64 + r]      = acc10[j];
      rd[(rr+32)*64 + 32 + r] = acc11[j];
    }
  }
  __syncthreads();
  if (kw == 0){
    float* rd = red + rh*12288;
    float* out = gP + ((size_t)kh*NNODE + rowbase)*HCOL;
    #pragma unroll
    for (int j=0; j<16; ++j){
      int rr = (j&3) + 8*(j>>2) + 4*hsub;
      float v00 = acc00[j] + rd[(rr   )*64+r]    + rd[4096+(rr   )*64+r]    + rd[8192+(rr   )*64+r];
      float v01 = acc01[j] + rd[(rr   )*64+32+r] + rd[4096+(rr   )*64+32+r] + rd[8192+(rr   )*64+32+r];
      float v10 = acc10[j] + rd[(rr+32)*64+r]    + rd[4096+(rr+32)*64+r]    + rd[8192+(rr+32)*64+r];
      float v11 = acc11[j] + rd[(rr+32)*64+32+r] + rd[4096+(rr+32)*64+32+r] + rd[8192+(rr+32)*64+32+r];
      out[(size_t)(rr     )*HCOL + r]      = v00;
      out[(size_t)(rr     )*HCOL + 32 + r] = v01;
      out[(size_t)(rr + 32)*HCOL + r]      = v10;
      out[(size_t)(rr + 32)*HCOL + 32 + r] = v11;
    }
  }
}

// ---------------- reduce: g = relu(gP[0] + gP[1] + bias) ----------------
__global__ __launch_bounds__(256) void reduce_kernel(
    const float* __restrict__ gP,    // [2][16384][64]
    const float* __restrict__ bias,  // [64]
    float* __restrict__ g)           // [16384][64]
{
  const size_t i = (size_t)blockIdx.x * 256 + threadIdx.x;   // f32x4 index
  const f32x4v* p = (const f32x4v*)gP;
  f32x4v s = p[i] + p[i + 262144];
  f32x4v b = *(const f32x4v*)(bias + (i & 15) * 4);
  f32x4v o;
  o[0] = fmaxf(s[0] + b[0], 0.f);
  o[1] = fmaxf(s[1] + b[1], 0.f);
  o[2] = fmaxf(s[2] + b[2], 0.f);
  o[3] = fmaxf(s[3] + b[3], 0.f);
  ((f32x4v*)g)[i] = o;
}

// ---------------- projection: out[h][n] = sum_f in[n][f]*W[f][h], bf16 out ----------------
template<int F>
__global__ __launch_bounds__(128) void proj_T_kernel(
    const float* __restrict__ in,   // [N][F]
    const float* __restrict__ W,    // [F][64]
    __bf16* __restrict__ out)       // [64][N]
{
  constexpr int FP = F + 4;
  __shared__ float sWt[64*FP];
  __shared__ short sOut[64*136];

  int tid = threadIdx.x;
  for (int e = tid; e < 64*F; e += 128){
    int h = e / F, j = e - h*F;
    sWt[h*FP + j] = W[j*64 + h];
  }
  __syncthreads();

  const size_t n = (size_t)blockIdx.x*128 + tid;
  float rowv[F];
  #pragma unroll
  for (int j=0; j<F; j+=4){
    f32x4v v = *(const f32x4v*)(in + n*F + j);
    rowv[j]=v[0]; rowv[j+1]=v[1]; rowv[j+2]=v[2]; rowv[j+3]=v[3];
  }
  #pragma unroll
  for (int h=0; h<64; ++h){
    float s = 0.f;
    #pragma unroll
    for (int j=0; j<F; j+=4){
      f32x4v w = *(const f32x4v*)&sWt[h*FP + j];
      s += rowv[j]*w[0] + rowv[j+1]*w[1] + rowv[j+2]*w[2] + rowv[j+3]*w[3];
    }
    sOut[h*136 + tid] = __builtin_bit_cast(short, (__bf16)s);
  }
  __syncthreads();

  const size_t n0 = (size_t)blockIdx.x*128;
  #pragma unroll
  for (int pi=0; pi<8; ++pi){
    int p = pi*128 + tid;
    int h = p >> 4, cc = p & 15;
    i32x4 v = *(const i32x4*)&sOut[h*136 + cc*8];
    *(i32x4*)(out + (size_t)h*NNODE + n0 + cc*8) = v;
  }
}

// ---------------- tail MLP: out[n] = relu(g2[n]@Wd1+bd1)@Wd2 + bd2 ----------------
__global__ __launch_bounds__(256) void tail_kernel(
    const float* __restrict__ g2,
    const float* __restrict__ Wd1,
    const float* __restrict__ bd1,
    const float* __restrict__ Wd2,
    const float* __restrict__ bd2,
    float* __restrict__ outp)
{
  __shared__ float sW[64*32];
  __shared__ float sb1[32], sw2[32];
  int tid = threadIdx.x;
  for (int e=tid; e<2048; e+=256) sW[e] = Wd1[e];
  if (tid < 32){ sb1[tid] = bd1[tid]; sw2[tid] = Wd2[tid]; }
  __syncthreads();

  size_t n = (size_t)blockIdx.x*256 + tid;
  float rv[64];
  #pragma unroll
  for (int j=0;j<64;j+=4){
    f32x4v v = *(const f32x4v*)(g2 + n*64 + j);
    rv[j]=v[0]; rv[j+1]=v[1]; rv[j+2]=v[2]; rv[j+3]=v[3];
  }
  float o = 0.f;
  #pragma unroll
  for (int c=0;c<32;++c){
    float s = sb1[c];
    #pragma unroll
    for (int j=0;j<64;++j) s += rv[j]*sW[j*32 + c];
    o += fmaxf(s, 0.f) * sw2[c];
  }
  outp[n] = o + bd2[0];
}

extern "C" void kernel_launch(void* const* d_in, const int* in_sizes, int n_in,
                              void* d_out, int out_size, void* d_ws, size_t ws_size,
                              hipStream_t stream)
{
  const float* x   = (const float*)d_in[0];
  const float* a   = (const float*)d_in[1];
  const float* W1  = (const float*)d_in[2];
  const float* b1  = (const float*)d_in[3];
  const float* W2  = (const float*)d_in[4];
  const float* b2  = (const float*)d_in[5];
  const float* Wd1 = (const float*)d_in[6];
  const float* bd1 = (const float*)d_in[7];
  const float* Wd2 = (const float*)d_in[8];
  const float* bd2 = (const float*)d_in[9];
  float* outp = (float*)d_out;

  char* ws = (char*)d_ws;                       // needs 20 MB
  __bf16* Ht1 = (__bf16*)(ws);                  // [64][16384] bf16, 2 MB
  __bf16* Ht2 = (__bf16*)(ws + (2u<<20));       // 2 MB
  float*  g1  = (float*)(ws + (4u<<20));        // [16384][64] f32, 4 MB
  float*  g2  = (float*)(ws + (8u<<20));        // 4 MB
  float*  gP  = (float*)(ws + (12u<<20));       // [2][16384][64] f32, 8 MB

  proj_T_kernel<32><<<128, 128, 0, stream>>>(x,  W1, Ht1);
  gcn_layer_kernel <<<256, 512, 0, stream>>>(a, Ht1, gP);
  reduce_kernel    <<<1024, 256, 0, stream>>>(gP, b1, g1);
  proj_T_kernel<64><<<128, 128, 0, stream>>>(g1, W2, Ht2);
  gcn_layer_kernel <<<256, 512, 0, stream>>>(a, Ht2, gP);
  reduce_kernel    <<<1024, 256, 0, stream>>>(gP, b2, g2);
  tail_kernel      <<<64, 256, 0, stream>>>(g2, Wd1, bd1, Wd2, bd2, outp);
}